// Round 1
// baseline (667.602 us; speedup 1.0000x reference)
//
#include <hip/hip_runtime.h>
#include <math.h>

#define IN_DIM 256
#define OUT_DIM 64
#define NEG_SLOPE 0.2f
#define EPS_GAT 1e-9f

// ---------------------------------------------------------------------------
// K1: h = X @ W^T  [N,64], a_src = h @ attn[:64], a_dst = h @ attn[64:]
// W (64KB) staged in LDS with XOR float4 swizzle (breaks same-bank-column
// pattern of 1KB-stride rows). Each wave processes 8 nodes per W-pass so the
// LDS W-read traffic is amortized 8x. lane = output dim.
// ---------------------------------------------------------------------------
__global__ __launch_bounds__(256) void gat_k1_linear(
    const float* __restrict__ X, const float* __restrict__ W,
    const float* __restrict__ attn, float* __restrict__ h,
    float* __restrict__ a_s, float* __restrict__ a_d, int N)
{
    __shared__ float4 sW4[OUT_DIM * IN_DIM / 4]; // 4096 float4 = 64KB
    const float4* W4 = (const float4*)W;
    for (int i = threadIdx.x; i < OUT_DIM * IN_DIM / 4; i += 256)
        sW4[i ^ ((i >> 6) & 7)] = W4[i];   // row-dependent XOR of f4-column
    __syncthreads();

    const int lane = threadIdx.x & 63;
    const int wave = threadIdx.x >> 6;
    const float at_s = attn[lane];
    const float at_d = attn[OUT_DIM + lane];
    const int wrow = lane * (IN_DIM / 4);
    const int wswz = lane & 7;

    const int gw = blockIdx.x * 4 + wave;  // global wave id
    const int nw = gridDim.x * 4;          // total waves

    for (int n0 = gw * 8; n0 < N; n0 += nw * 8) {
        const int m_max = min(8, N - n0);
        float acc[8] = {0.f,0.f,0.f,0.f,0.f,0.f,0.f,0.f};
        if (m_max == 8) {
            #pragma unroll 2
            for (int k4 = 0; k4 < IN_DIM / 4; ++k4) {
                float4 wv = sW4[(wrow + k4) ^ wswz];
                #pragma unroll
                for (int m = 0; m < 8; ++m) {
                    float4 xv = *((const float4*)(X + (size_t)(n0 + m) * IN_DIM) + k4);
                    acc[m] += xv.x * wv.x + xv.y * wv.y + xv.z * wv.z + xv.w * wv.w;
                }
            }
        } else {
            for (int k4 = 0; k4 < IN_DIM / 4; ++k4) {
                float4 wv = sW4[(wrow + k4) ^ wswz];
                for (int m = 0; m < m_max; ++m) {
                    float4 xv = *((const float4*)(X + (size_t)(n0 + m) * IN_DIM) + k4);
                    acc[m] += xv.x * wv.x + xv.y * wv.y + xv.z * wv.z + xv.w * wv.w;
                }
            }
        }
        for (int m = 0; m < m_max; ++m) {
            const int n = n0 + m;
            h[(size_t)n * OUT_DIM + lane] = acc[m];
            float vs = acc[m] * at_s;
            float vd = acc[m] * at_d;
            #pragma unroll
            for (int off = 32; off; off >>= 1) {
                vs += __shfl_down(vs, off);
                vd += __shfl_down(vd, off);
            }
            if (lane == 0) { a_s[n] = vs; a_d[n] = vd; }
        }
    }
}

// ---------------------------------------------------------------------------
// K2: histogram of dst -> counts[N]
// ---------------------------------------------------------------------------
__global__ __launch_bounds__(256) void gat_k2_hist(
    const int* __restrict__ dst, int* __restrict__ counts, int E)
{
    for (int i = blockIdx.x * 256 + threadIdx.x; i < E; i += gridDim.x * 256)
        atomicAdd(&counts[dst[i]], 1);
}

// ---------------------------------------------------------------------------
// K3: per-block exclusive scan of counts; block base assigned via a global
// atomic allocator (segment ordering across blocks is irrelevant -> no
// multi-kernel scan needed).
// ---------------------------------------------------------------------------
__global__ __launch_bounds__(1024) void gat_k3_scan(
    const int* __restrict__ counts, int* __restrict__ offsets,
    int* __restrict__ allocCursor, int N)
{
    __shared__ int wsum[16];
    __shared__ int blockBase;
    const int n = blockIdx.x * 1024 + threadIdx.x;
    const int lane = threadIdx.x & 63;
    const int wave = threadIdx.x >> 6;
    const int v = (n < N) ? counts[n] : 0;
    int incl = v;
    #pragma unroll
    for (int off = 1; off < 64; off <<= 1) {
        int t = __shfl_up(incl, off);
        if (lane >= off) incl += t;
    }
    if (lane == 63) wsum[wave] = incl;
    __syncthreads();
    if (wave == 0) {
        int wv = (lane < 16) ? wsum[lane] : 0;
        int wincl = wv;
        #pragma unroll
        for (int off = 1; off < 16; off <<= 1) {
            int t = __shfl_up(wincl, off);
            if (lane >= off) wincl += t;
        }
        if (lane < 16) wsum[lane] = wincl - wv;      // exclusive wave offsets
        if (lane == 15) blockBase = atomicAdd(allocCursor, wincl); // block total
    }
    __syncthreads();
    if (n < N) offsets[n] = blockBase + wsum[wave] + (incl - v);
}

// ---------------------------------------------------------------------------
// K4: scatter edges into dst-grouped order; compute e = leakyrelu(a_s+a_d)
// ---------------------------------------------------------------------------
__global__ __launch_bounds__(256) void gat_k4_scatter(
    const int* __restrict__ src, const int* __restrict__ dst,
    const float* __restrict__ a_s, const float* __restrict__ a_d,
    const int* __restrict__ offsets, int* __restrict__ cursor,
    int* __restrict__ sorted_src, float* __restrict__ sorted_e, int E)
{
    for (int i = blockIdx.x * 256 + threadIdx.x; i < E; i += gridDim.x * 256) {
        const int s = src[i], d = dst[i];
        float e = a_s[s] + a_d[d];
        e = (e >= 0.f) ? e : NEG_SLOPE * e;
        const int pos = offsets[d] + atomicAdd(&cursor[d], 1);
        sorted_src[pos] = s;
        sorted_e[pos] = e;
    }
}

// ---------------------------------------------------------------------------
// K5: one wave per dst node. lane = output dim. Segment softmax in registers
// (shfl reductions), then per-edge coalesced 256B gather of h[src] rows.
// Zero atomics; out written exactly once.
// ---------------------------------------------------------------------------
__global__ __launch_bounds__(256) void gat_k5_aggregate(
    const float* __restrict__ h, const float* __restrict__ sorted_e,
    const int* __restrict__ sorted_src, const int* __restrict__ offsets,
    const int* __restrict__ counts, const float* __restrict__ bias,
    float* __restrict__ out, int N)
{
    const int wave = threadIdx.x >> 6, lane = threadIdx.x & 63;
    const int d = blockIdx.x * 4 + wave;
    if (d >= N) return;
    const int deg = counts[d], base = offsets[d];

    float m = -INFINITY;
    for (int j = lane; j < deg; j += 64) m = fmaxf(m, sorted_e[base + j]);
    #pragma unroll
    for (int off = 32; off; off >>= 1) m = fmaxf(m, __shfl_xor(m, off));

    float ssum = 0.f;
    for (int j = lane; j < deg; j += 64) ssum += __expf(sorted_e[base + j] - m);
    #pragma unroll
    for (int off = 32; off; off >>= 1) ssum += __shfl_xor(ssum, off);
    const float inv = 1.f / (ssum + EPS_GAT);

    float acc = 0.f;
    for (int j0 = 0; j0 < deg; j0 += 64) {
        const int jj = j0 + lane;
        float wgt = 0.f; int s_ = 0;
        if (jj < deg) {
            wgt = __expf(sorted_e[base + jj] - m) * inv;
            s_  = sorted_src[base + jj];
        }
        const int cnt = min(64, deg - j0);
        for (int t = 0; t < cnt; ++t) {
            const float a = __shfl(wgt, t);
            const int   s = __shfl(s_, t);
            acc += a * h[(size_t)s * OUT_DIM + lane];
        }
    }
    out[(size_t)d * OUT_DIM + lane] = acc + bias[lane];
}

// ---------------------------------------------------------------------------
extern "C" void kernel_launch(void* const* d_in, const int* in_sizes, int n_in,
                              void* d_out, int out_size, void* d_ws, size_t ws_size,
                              hipStream_t stream)
{
    const float* X    = (const float*)d_in[0];
    const int*   EI   = (const int*)d_in[1];
    const float* W    = (const float*)d_in[2];
    const float* attn = (const float*)d_in[3];
    const float* bias = (const float*)d_in[4];
    float* out = (float*)d_out;

    const int N = in_sizes[0] / IN_DIM;
    const int E = in_sizes[1] / 2;
    const int* src = EI;
    const int* dst = EI + E;

    // workspace layout (h first for 16B alignment)
    char* ws = (char*)d_ws;
    float* h      = (float*)ws; ws += (size_t)N * OUT_DIM * sizeof(float);
    float* a_s    = (float*)ws; ws += (size_t)N * sizeof(float);
    float* a_d    = (float*)ws; ws += (size_t)N * sizeof(float);
    int*   counts = (int*)ws;   ws += (size_t)N * sizeof(int);   // zeroed
    int*   cursor = (int*)ws;   ws += (size_t)N * sizeof(int);   // zeroed
    int*   alloc  = (int*)ws;   ws += 256;                       // zeroed
    int*   offsets= (int*)ws;   ws += (size_t)N * sizeof(int);
    int*   sorted_src = (int*)ws;   ws += (size_t)E * sizeof(int);
    float* sorted_e   = (float*)ws; ws += (size_t)E * sizeof(float);

    // zero counts+cursor+alloc (contiguous)
    hipMemsetAsync(counts, 0, (size_t)(2 * N) * sizeof(int) + 256, stream);

    gat_k1_linear<<<512, 256, 0, stream>>>(X, W, attn, h, a_s, a_d, N);
    gat_k2_hist<<<2048, 256, 0, stream>>>(dst, counts, E);
    gat_k3_scan<<<(N + 1023) / 1024, 1024, 0, stream>>>(counts, offsets, alloc, N);
    gat_k4_scatter<<<2048, 256, 0, stream>>>(src, dst, a_s, a_d, offsets, cursor,
                                             sorted_src, sorted_e, E);
    gat_k5_aggregate<<<(N + 3) / 4, 256, 0, stream>>>(h, sorted_e, sorted_src,
                                                      offsets, counts, bias, out, N);
}

// Round 3
// 413.142 us; speedup vs baseline: 1.6159x; 1.6159x over previous
//
#include <hip/hip_runtime.h>
#include <math.h>

#define IN_DIM 256
#define OUT_DIM 64
#define NEG_SLOPE 0.2f
#define EPS_GAT 1e-9f

// ---------------------------------------------------------------------------
// K1: register-tiled fp32 GEMM  h = X @ W^T  [N,64], fused
//     a_src = h @ attn[:64], a_dst = h @ attn[64:]
// BM=128 nodes, BN=64 dims (all), BK=32. 128 threads = 16(ty) x 8(tx),
// thread tile 8 nodes x 8 dims = 64 acc VGPRs.
// LDS tiles stored k-major (transposed on stage) so compute reads are
// ds_read_b128: per kk, 2x float4 X + 2x float4 W = 64B per 64 FMA.
// Pads (132/68) keep reads 2-way (free), stage writes <=4-way.
// ---------------------------------------------------------------------------
__global__ __launch_bounds__(128) void gat_k1_linear(
    const float* __restrict__ X, const float* __restrict__ W,
    const float* __restrict__ attn, float* __restrict__ h,
    float* __restrict__ a_s, float* __restrict__ a_d, int N)
{
    __shared__ float sX[32 * 132];  // [k][node], 16.9 KB
    __shared__ float sW[32 * 68];   // [k][dim],   8.7 KB

    const int tid = threadIdx.x;
    const int tx = tid & 7;         // dim group   (8 dims each)
    const int ty = tid >> 3;        // node group  (8 nodes each), 0..15
    const int n0 = blockIdx.x * 128;

    const float4* X4 = (const float4*)X;
    const float4* W4 = (const float4*)W;

    float acc[8][8];
    #pragma unroll
    for (int i = 0; i < 8; ++i)
        #pragma unroll
        for (int j = 0; j < 8; ++j) acc[i][j] = 0.f;

    // attn slices for fused epilogue
    float as_r[8], ad_r[8];
    #pragma unroll
    for (int j = 0; j < 8; ++j) {
        as_r[j] = attn[tx * 8 + j];
        ad_r[j] = attn[OUT_DIM + tx * 8 + j];
    }

    const int xc4 = tid & 7;   // float4 col within 32-col tile
    const int xr0 = tid >> 3;  // row 0..15

    for (int k0 = 0; k0 < IN_DIM; k0 += 32) {
        const int k0c4 = k0 >> 2;
        __syncthreads();
        // ---- stage X tile [128 rows][32 cols] -> sX[k][node]
        #pragma unroll
        for (int p = 0; p < 8; ++p) {
            const int row = p * 16 + xr0;
            int n = n0 + row; if (n >= N) n = N - 1;
            float4 v = X4[(size_t)n * 64 + k0c4 + xc4];
            const int kb = xc4 * 4;
            sX[(kb + 0) * 132 + row] = v.x;
            sX[(kb + 1) * 132 + row] = v.y;
            sX[(kb + 2) * 132 + row] = v.z;
            sX[(kb + 3) * 132 + row] = v.w;
        }
        // ---- stage W tile [64 rows][32 cols] -> sW[k][dim]
        #pragma unroll
        for (int p = 0; p < 4; ++p) {
            const int idx = p * 128 + tid;
            const int o = idx >> 3, c4 = idx & 7;
            float4 v = W4[(size_t)o * 64 + k0c4 + c4];
            const int kb = c4 * 4;
            sW[(kb + 0) * 68 + o] = v.x;
            sW[(kb + 1) * 68 + o] = v.y;
            sW[(kb + 2) * 68 + o] = v.z;
            sW[(kb + 3) * 68 + o] = v.w;
        }
        __syncthreads();
        // ---- compute
        #pragma unroll 2
        for (int kk = 0; kk < 32; ++kk) {
            const float4* xp = (const float4*)&sX[kk * 132 + ty * 8];
            const float4* wp = (const float4*)&sW[kk * 68 + tx * 8];
            float4 xa = xp[0], xb = xp[1];
            float4 wa = wp[0], wb = wp[1];
            float xv[8] = {xa.x, xa.y, xa.z, xa.w, xb.x, xb.y, xb.z, xb.w};
            float wv[8] = {wa.x, wa.y, wa.z, wa.w, wb.x, wb.y, wb.z, wb.w};
            #pragma unroll
            for (int i = 0; i < 8; ++i)
                #pragma unroll
                for (int j = 0; j < 8; ++j) acc[i][j] += xv[i] * wv[j];
        }
    }

    // ---- epilogue: write h, fused a_s/a_d (reduce over tx lanes)
    float4* h4 = (float4*)h;
    #pragma unroll
    for (int m = 0; m < 8; ++m) {
        const int n = n0 + ty * 8 + m;
        float vs = 0.f, vd = 0.f;
        #pragma unroll
        for (int j = 0; j < 8; ++j) { vs += acc[m][j] * as_r[j]; vd += acc[m][j] * ad_r[j]; }
        vs += __shfl_xor(vs, 1); vs += __shfl_xor(vs, 2); vs += __shfl_xor(vs, 4);
        vd += __shfl_xor(vd, 1); vd += __shfl_xor(vd, 2); vd += __shfl_xor(vd, 4);
        if (n < N) {
            float4 lo = {acc[m][0], acc[m][1], acc[m][2], acc[m][3]};
            float4 hi = {acc[m][4], acc[m][5], acc[m][6], acc[m][7]};
            h4[(size_t)n * 16 + tx * 2]     = lo;
            h4[(size_t)n * 16 + tx * 2 + 1] = hi;
            if (tx == 0) { a_s[n] = vs; a_d[n] = vd; }
        }
    }
}

// ---------------------------------------------------------------------------
// K2: histogram of dst -> counts[N]
// ---------------------------------------------------------------------------
__global__ __launch_bounds__(256) void gat_k2_hist(
    const int* __restrict__ dst, int* __restrict__ counts, int E)
{
    for (int i = blockIdx.x * 256 + threadIdx.x; i < E; i += gridDim.x * 256)
        atomicAdd(&counts[dst[i]], 1);
}

// ---------------------------------------------------------------------------
// K3: exclusive scan of counts; block bases via global atomic allocator
// (cross-block segment order is irrelevant).
// ---------------------------------------------------------------------------
__global__ __launch_bounds__(1024) void gat_k3_scan(
    const int* __restrict__ counts, int* __restrict__ offsets,
    int* __restrict__ allocCursor, int N)
{
    __shared__ int wsum[16];
    __shared__ int blockBase;
    const int n = blockIdx.x * 1024 + threadIdx.x;
    const int lane = threadIdx.x & 63;
    const int wave = threadIdx.x >> 6;
    const int v = (n < N) ? counts[n] : 0;
    int incl = v;
    #pragma unroll
    for (int off = 1; off < 64; off <<= 1) {
        int t = __shfl_up(incl, off);
        if (lane >= off) incl += t;
    }
    if (lane == 63) wsum[wave] = incl;
    __syncthreads();
    if (wave == 0) {
        int wv = (lane < 16) ? wsum[lane] : 0;
        int wincl = wv;
        #pragma unroll
        for (int off = 1; off < 16; off <<= 1) {
            int t = __shfl_up(wincl, off);
            if (lane >= off) wincl += t;
        }
        if (lane < 16) wsum[lane] = wincl - wv;
        if (lane == 15) blockBase = atomicAdd(allocCursor, wincl);
    }
    __syncthreads();
    if (n < N) offsets[n] = blockBase + wsum[wave] + (incl - v);
}

// ---------------------------------------------------------------------------
// K4: scatter edges into dst-grouped order as packed int2{src, e_bits}
// (one 8B random store per edge instead of two 4B line touches)
// ---------------------------------------------------------------------------
__global__ __launch_bounds__(256) void gat_k4_scatter(
    const int* __restrict__ src, const int* __restrict__ dst,
    const float* __restrict__ a_s, const float* __restrict__ a_d,
    const int* __restrict__ offsets, int* __restrict__ cursor,
    int2* __restrict__ packed, int E)
{
    for (int i = blockIdx.x * 256 + threadIdx.x; i < E; i += gridDim.x * 256) {
        const int s = src[i], d = dst[i];
        float e = a_s[s] + a_d[d];
        e = (e >= 0.f) ? e : NEG_SLOPE * e;
        const int pos = offsets[d] + atomicAdd(&cursor[d], 1);
        packed[pos] = make_int2(s, __float_as_int(e));
    }
}

// ---------------------------------------------------------------------------
// K5: one wave per dst. Slot decomposition: 64 lanes = 4 edges x 16 dim-
// quarters; one float4 gather instruction covers 4 h-rows (1KB coalesced).
// deg<=64 fast path keeps e in registers (single load, shfl-xor softmax).
// Cross-slot shfl_xor reduce; out written exactly once, zero atomics.
// ---------------------------------------------------------------------------
__global__ __launch_bounds__(256) void gat_k5_aggregate(
    const float* __restrict__ h, const int2* __restrict__ packed,
    const int* __restrict__ offsets, const int* __restrict__ counts,
    const float* __restrict__ bias, float* __restrict__ out, int N)
{
    const int wave = threadIdx.x >> 6, lane = threadIdx.x & 63;
    const int d = blockIdx.x * 4 + wave;
    if (d >= N) return;
    const int deg = counts[d], base = offsets[d];
    const int slot = lane >> 4, q = lane & 15;
    const float4* h4 = (const float4*)h;

    float4 acc = {0.f, 0.f, 0.f, 0.f};

    if (deg <= 64) {
        int s = 0; float e = -INFINITY;
        if (lane < deg) { int2 pe = packed[base + lane]; s = pe.x; e = __int_as_float(pe.y); }
        float m = e;
        #pragma unroll
        for (int off = 32; off; off >>= 1) m = fmaxf(m, __shfl_xor(m, off));
        float p = (lane < deg) ? __expf(e - m) : 0.f;
        float sum = p;
        #pragma unroll
        for (int off = 32; off; off >>= 1) sum += __shfl_xor(sum, off);
        const float w = p / (sum + EPS_GAT);
        for (int t0 = 0; t0 < deg; t0 += 4) {
            const float wg = __shfl(w, t0 + slot);
            const int  sid = __shfl(s, t0 + slot);
            float4 hv = h4[(size_t)sid * 16 + q];
            acc.x += wg * hv.x; acc.y += wg * hv.y;
            acc.z += wg * hv.z; acc.w += wg * hv.w;
        }
    } else {
        float m = -INFINITY;
        for (int j = lane; j < deg; j += 64)
            m = fmaxf(m, __int_as_float(packed[base + j].y));
        #pragma unroll
        for (int off = 32; off; off >>= 1) m = fmaxf(m, __shfl_xor(m, off));
        float sum = 0.f;
        for (int j = lane; j < deg; j += 64)
            sum += __expf(__int_as_float(packed[base + j].y) - m);
        #pragma unroll
        for (int off = 32; off; off >>= 1) sum += __shfl_xor(sum, off);
        const float inv = 1.f / (sum + EPS_GAT);
        for (int j0 = 0; j0 < deg; j0 += 64) {
            int s = 0; float w = 0.f;
            if (j0 + lane < deg) {
                int2 pe = packed[base + j0 + lane];
                s = pe.x;
                w = __expf(__int_as_float(pe.y) - m) * inv;
            }
            const int cnt = min(64, deg - j0);
            for (int t0 = 0; t0 < cnt; t0 += 4) {
                const float wg = __shfl(w, t0 + slot);
                const int  sid = __shfl(s, t0 + slot);
                float4 hv = h4[(size_t)sid * 16 + q];
                acc.x += wg * hv.x; acc.y += wg * hv.y;
                acc.z += wg * hv.z; acc.w += wg * hv.w;
            }
        }
    }

    // reduce across the 4 slots
    acc.x += __shfl_xor(acc.x, 16); acc.x += __shfl_xor(acc.x, 32);
    acc.y += __shfl_xor(acc.y, 16); acc.y += __shfl_xor(acc.y, 32);
    acc.z += __shfl_xor(acc.z, 16); acc.z += __shfl_xor(acc.z, 32);
    acc.w += __shfl_xor(acc.w, 16); acc.w += __shfl_xor(acc.w, 32);

    if (slot == 0) {
        const float4* b4 = (const float4*)bias;
        float4 bv = b4[q];
        float4 o;
        o.x = acc.x + bv.x; o.y = acc.y + bv.y;
        o.z = acc.z + bv.z; o.w = acc.w + bv.w;
        ((float4*)out)[(size_t)d * 16 + q] = o;
    }
}

// ---------------------------------------------------------------------------
extern "C" void kernel_launch(void* const* d_in, const int* in_sizes, int n_in,
                              void* d_out, int out_size, void* d_ws, size_t ws_size,
                              hipStream_t stream)
{
    const float* X    = (const float*)d_in[0];
    const int*   EI   = (const int*)d_in[1];
    const float* W    = (const float*)d_in[2];
    const float* attn = (const float*)d_in[3];
    const float* bias = (const float*)d_in[4];
    float* out = (float*)d_out;

    const int N = in_sizes[0] / IN_DIM;
    const int E = in_sizes[1] / 2;
    const int* src = EI;
    const int* dst = EI + E;

    // workspace layout (16B-aligned blocks)
    char* ws = (char*)d_ws;
    float* h      = (float*)ws; ws += (size_t)N * OUT_DIM * sizeof(float);
    float* a_s    = (float*)ws; ws += (size_t)N * sizeof(float);
    float* a_d    = (float*)ws; ws += (size_t)N * sizeof(float);
    int*   counts = (int*)ws;   ws += (size_t)N * sizeof(int);   // zeroed
    int*   cursor = (int*)ws;   ws += (size_t)N * sizeof(int);   // zeroed
    int*   alloc  = (int*)ws;   ws += 256;                       // zeroed
    int*   offsets= (int*)ws;   ws += (size_t)N * sizeof(int);
    int2*  packed = (int2*)ws;  ws += (size_t)E * sizeof(int2);

    hipMemsetAsync(counts, 0, (size_t)(2 * N) * sizeof(int) + 256, stream);

    gat_k1_linear<<<(N + 127) / 128, 128, 0, stream>>>(X, W, attn, h, a_s, a_d, N);
    gat_k2_hist<<<2048, 256, 0, stream>>>(dst, counts, E);
    gat_k3_scan<<<(N + 1023) / 1024, 1024, 0, stream>>>(counts, offsets, alloc, N);
    gat_k4_scatter<<<2048, 256, 0, stream>>>(src, dst, a_s, a_d, offsets, cursor,
                                             packed, E);
    gat_k5_aggregate<<<(N + 3) / 4, 256, 0, stream>>>(h, packed, offsets, counts,
                                                      bias, out, N);
}